// Round 7
// baseline (139.491 us; speedup 1.0000x reference)
//
#include <hip/hip_runtime.h>

// segment_sum: out[col_idx[i]] += values[i], out = float32[n_cols].
// Inputs: d_in[0]=row_idx (UNUSED), d_in[1]=col_idx (i32), d_in[2]=values (f32),
// d_in[3]=n_rows, d_in[4]=n_cols.
//
// Lessons:
//  r2: global f32 atomics = 32B write-through @ ~20G/s regardless of scope.
//  r5/r6: NOT traffic-bound (3x HBM traffic, same time; XCD fix, same time).
//      Bound by per-CU streaming rate ~7-8.4 B/cyc/CU. f32 hist 400KB vs
//      160KB LDS forces R=3 passes. -> use ALL 256 CUs, deepen MLP.
// This round: grid=256 (ranges {86,85,85}), 8-deep prefetch, tail in reduce.

constexpr int R  = 3;       // column ranges (passes over the input)
constexpr int RS = 33336;   // columns per range; R*RS >= 100000; 133.3KB LDS
#define TPB 1024

__device__ __forceinline__ void proc4(const int4& c, const float4& val,
                                      int base, float* hist) {
    unsigned d;
    d = (unsigned)(c.x - base); if (d < (unsigned)RS) atomicAdd(&hist[d], val.x);
    d = (unsigned)(c.y - base); if (d < (unsigned)RS) atomicAdd(&hist[d], val.y);
    d = (unsigned)(c.z - base); if (d < (unsigned)RS) atomicAdd(&hist[d], val.z);
    d = (unsigned)(c.w - base); if (d < (unsigned)RS) atomicAdd(&hist[d], val.w);
}

__global__ __launch_bounds__(TPB)
void scatter_lds_kernel(const int* __restrict__ col_idx,
                        const float* __restrict__ values,
                        float* __restrict__ ws,
                        int nvec, int s1, int s2,
                        int per0, int per1, int per2) {
    __shared__ float hist[RS];

    const int id = blockIdx.x;
    int r, b, per;
    if (id < s1)      { r = 0; b = id;      per = per0; }
    else if (id < s2) { r = 1; b = id - s1; per = per1; }
    else              { r = 2; b = id - s2; per = per2; }
    const int base = r * RS;

    for (int i = threadIdx.x; i < RS; i += TPB) hist[i] = 0.0f;
    __syncthreads();

    const int v0 = b * per;
    const int v1 = min(nvec, v0 + per);

    const int4*   c4 = reinterpret_cast<const int4*>(col_idx);
    const float4* v4 = reinterpret_cast<const float4*>(values);

    int v = v0 + threadIdx.x;
    // 8-deep prefetch: 16 loads (256 B/thread) in flight before consumption
    for (; v + 7 * TPB < v1; v += 8 * TPB) {
        int4   c0 = c4[v];             float4 x0 = v4[v];
        int4   c1 = c4[v + 1 * TPB];   float4 x1 = v4[v + 1 * TPB];
        int4   c2 = c4[v + 2 * TPB];   float4 x2 = v4[v + 2 * TPB];
        int4   c3 = c4[v + 3 * TPB];   float4 x3 = v4[v + 3 * TPB];
        int4   c4v = c4[v + 4 * TPB];  float4 x4 = v4[v + 4 * TPB];
        int4   c5 = c4[v + 5 * TPB];   float4 x5 = v4[v + 5 * TPB];
        int4   c6 = c4[v + 6 * TPB];   float4 x6 = v4[v + 6 * TPB];
        int4   c7 = c4[v + 7 * TPB];   float4 x7 = v4[v + 7 * TPB];
        proc4(c0, x0, base, hist);
        proc4(c1, x1, base, hist);
        proc4(c2, x2, base, hist);
        proc4(c3, x3, base, hist);
        proc4(c4v, x4, base, hist);
        proc4(c5, x5, base, hist);
        proc4(c6, x6, base, hist);
        proc4(c7, x7, base, hist);
    }
    // cleanup with distance-1 rolling prefetch
    if (v < v1) {
        int4 cc = c4[v]; float4 xx = v4[v];
        for (v += TPB; v < v1; v += TPB) {
            int4 cn = c4[v]; float4 xn = v4[v];
            proc4(cc, xx, base, hist);
            cc = cn; xx = xn;
        }
        proc4(cc, xx, base, hist);
    }
    __syncthreads();

    // dump histogram (coalesced float4) to ws copy `id`
    float4* dst = reinterpret_cast<float4*>(ws + (size_t)id * RS);
    const float4* src = reinterpret_cast<const float4*>(hist);
    for (int i = threadIdx.x; i < (RS >> 2); i += TPB) dst[i] = src[i];
}

__global__ void reduce_kernel(const float* __restrict__ ws,
                              float* __restrict__ out,
                              int ncols, int B0, int B1, int B2,
                              const int* __restrict__ col_idx,
                              const float* __restrict__ values,
                              int nnz, int nvec) {
    int c = blockIdx.x * blockDim.x + threadIdx.x;
    if (c >= ncols) return;
    const int r     = c / RS;
    const int local = c - r * RS;
    const int start = (r == 0) ? 0 : (r == 1 ? B0 : B0 + B1);
    const int cnt   = (r == 0) ? B0 : (r == 1 ? B1 : B2);
    const float* p  = ws + (size_t)start * RS + local;
    float s = 0.0f;
    for (int b = 0; b < cnt; ++b) s += p[(size_t)b * RS];
    // tail elements (nnz % 4) — broadcast read, cheap
    for (int i = nvec << 2; i < nnz; ++i)
        if (col_idx[i] == c) s += values[i];
    out[c] = s;
}

// ---- fallback (tiny ws / large ncols): direct device-scope atomics ----
__global__ void zero_out_kernel(float* __restrict__ out, int n) {
    int i = blockIdx.x * blockDim.x + threadIdx.x;
    if (i < n) out[i] = 0.0f;
}
__global__ void scatter_add_kernel(const int* __restrict__ col_idx,
                                   const float* __restrict__ values,
                                   float* __restrict__ out, int nnz) {
    const int tid    = blockIdx.x * blockDim.x + threadIdx.x;
    const int stride = gridDim.x * blockDim.x;
    const int nvec = nnz >> 2;
    const int4*   c4 = reinterpret_cast<const int4*>(col_idx);
    const float4* v4 = reinterpret_cast<const float4*>(values);
    for (int v = tid; v < nvec; v += stride) {
        int4 c = c4[v]; float4 x = v4[v];
        atomicAdd(&out[c.x], x.x); atomicAdd(&out[c.y], x.y);
        atomicAdd(&out[c.z], x.z); atomicAdd(&out[c.w], x.w);
    }
    for (int i = (nvec << 2) + tid; i < nnz; i += stride)
        atomicAdd(&out[col_idx[i]], values[i]);
}

extern "C" void kernel_launch(void* const* d_in, const int* in_sizes, int n_in,
                              void* d_out, int out_size, void* d_ws, size_t ws_size,
                              hipStream_t stream) {
    const int*   col_idx = (const int*)d_in[1];
    const float* values  = (const float*)d_in[2];
    float*       out     = (float*)d_out;
    const int    nnz     = in_sizes[1];
    const int    ncols   = out_size;
    const int    nvec    = nnz >> 2;

    // total blocks = one per CU, bounded by ws capacity
    int G = (int)(ws_size / ((size_t)RS * sizeof(float)));
    if (G > 256) G = 256;

    if (ncols <= R * RS && G >= 24) {
        float* ws = (float*)d_ws;
        // split G blocks across 3 ranges as evenly as possible
        const int B0 = (G + 2) / 3;
        const int B1 = (G - B0 + 1) / 2;
        const int B2 = G - B0 - B1;
        const int s1 = B0, s2 = B0 + B1;
        const int per0 = (nvec + B0 - 1) / B0;
        const int per1 = (nvec + B1 - 1) / B1;
        const int per2 = (nvec + B2 - 1) / B2;
        scatter_lds_kernel<<<G, TPB, 0, stream>>>(col_idx, values, ws,
                                                  nvec, s1, s2,
                                                  per0, per1, per2);
        int blocks = (ncols + 255) / 256;
        reduce_kernel<<<blocks, 256, 0, stream>>>(ws, out, ncols, B0, B1, B2,
                                                  col_idx, values, nnz, nvec);
    } else {
        int blocks = (ncols + 255) / 256;
        zero_out_kernel<<<blocks, 256, 0, stream>>>(out, ncols);
        scatter_add_kernel<<<2048, 256, 0, stream>>>(col_idx, values, out, nnz);
    }
}